// Round 5
// baseline (315.187 us; speedup 1.0000x reference)
//
#include <hip/hip_runtime.h>

typedef unsigned short u16;
typedef unsigned int u32;
typedef __attribute__((ext_vector_type(8))) short bf16x8;
typedef __attribute__((ext_vector_type(4))) float f32x4;

__device__ __forceinline__ u16 f2bf(float f) {
    u32 u = __float_as_uint(f);
    u += 0x7fffu + ((u >> 16) & 1u);   // RNE
    return (u16)(u >> 16);
}

__device__ __forceinline__ void llds16(void* l, const void* g) {
    __builtin_amdgcn_global_load_lds(
        (const __attribute__((address_space(1))) u32*)g,
        (__attribute__((address_space(3))) u32*)l, 16, 0, 0);
}

// ---- prep (single dispatch): x NCHW f32 -> NHWC bf16, w -> [p][co][ci] bf16,
//      BN fold (s=g*rsqrt(v+eps), t=b-m*s), 2KB zero page ---------------------
__global__ void prep(const float* __restrict__ x, u16* __restrict__ xt,
                     const float* __restrict__ w1, const float* __restrict__ w2,
                     u16* __restrict__ W1t, u16* __restrict__ W2t,
                     const float* __restrict__ g1, const float* __restrict__ b1,
                     const float* __restrict__ rm1, const float* __restrict__ rv1,
                     const float* __restrict__ g2, const float* __restrict__ b2,
                     const float* __restrict__ rm2, const float* __restrict__ rv2,
                     float* __restrict__ sc, u32* __restrict__ zp) {
    int t = threadIdx.x;
    int b = blockIdx.x;
    if (b < 16384) {
        // x transpose: 64 n * 32 h * 8 cb blocks; 32c x 32w tile via LDS
        __shared__ float xl[32 * 33];
        int n = b >> 8, rem = b & 255;
        int h = rem >> 3, c0 = (rem & 7) << 5;
        int cl = t >> 5, w = t & 31;
#pragma unroll
        for (int i = 0; i < 4; ++i) {
            int c = c0 + i * 8 + cl;
            xl[(i * 8 + cl) * 33 + w] = x[(n * 256 + c) * 1024 + h * 32 + w];
        }
        __syncthreads();
        int wo = t >> 3, k = t & 7;
        ushort4 o;
        o.x = f2bf(xl[(k * 4 + 0) * 33 + wo]);
        o.y = f2bf(xl[(k * 4 + 1) * 33 + wo]);
        o.z = f2bf(xl[(k * 4 + 2) * 33 + wo]);
        o.w = f2bf(xl[(k * 4 + 3) * 33 + wo]);
        *(ushort4*)&xt[((n * 32 + h) * 32 + wo) * 256 + c0 + k * 4] = o;
    } else {
        int bb = b - 16384;                     // 0..511
        int idx = (bb & 255) * 256 + t;         // (co,ci) pair
        const float* src = (bb >> 8) ? w2 : w1;
        u16* dst = (bb >> 8) ? W2t : W1t;
        const float* s = src + idx * 9;
        int co = idx >> 8, ci = idx & 255;
#pragma unroll
        for (int p = 0; p < 9; ++p)
            dst[p * 65536 + co * 256 + ci] = f2bf(s[p]);
        if (bb == 0) {
            float s1 = g1[t] * rsqrtf(rv1[t] + 1e-5f);
            sc[t]       = s1;
            sc[256 + t] = b1[t] - rm1[t] * s1;
            float s2 = g2[t] * rsqrtf(rv2[t] + 1e-5f);
            sc[512 + t] = s2;
            sc[768 + t] = b2[t] - rm2[t] * s2;
            zp[t] = 0u;            // 2KB zero page (512 u32)
            zp[t + 256] = 0u;
        }
    }
}

// read one kw-group into register buffer G: 8 B-frags + 12 A-frags (80 VGPR)
#define READ_GRP(G, KW) do {                                                   \
    _Pragma("unroll")                                                          \
    for (int r = 0; r < 4; ++r)                                                \
        _Pragma("unroll")                                                      \
        for (int hf = 0; hf < 2; ++hf)                                         \
            Bf[G][r][hf] = *(const bf16x8*)                                    \
                &pB[((wv * 2 + r) * 136 +                                      \
                     (((hf << 4) + n16 + (KW)) << 2) + q) << 3];               \
    _Pragma("unroll")                                                          \
    for (int kh = 0; kh < 3; ++kh) {                                           \
        const int p_ = kh * 3 + (KW);                                          \
        _Pragma("unroll")                                                      \
        for (int mt = 0; mt < 4; ++mt)                                         \
            Af[G][kh][mt] = *(const bf16x8*)                                   \
                &pA[((p_ << 8) + (mt << 6) + lane) << 3];                      \
    }                                                                          \
} while (0)

// 48 MFMA consuming register group G (16 independent acc chains of depth 3)
#define CLUSTER(G) do {                                                        \
    _Pragma("unroll")                                                          \
    for (int kh = 0; kh < 3; ++kh)                                             \
        _Pragma("unroll")                                                      \
        for (int mt = 0; mt < 4; ++mt)                                         \
            _Pragma("unroll")                                                  \
            for (int nt = 0; nt < 4; ++nt)                                     \
                acc[mt][nt] = __builtin_amdgcn_mfma_f32_16x16x32_bf16(         \
                    Af[G][kh][mt], Bf[G][(nt >> 1) + kh][nt & 1],              \
                    acc[mt][nt], 0, 0, 0);                                     \
} while (0)

// ---- main: fused conv3x3 + BN (+skip) + ReLU via MFMA implicit GEMM --------
// Block: 64 c_out x (16h x 32w), 8 waves (512 thr), wave = 64co x 64sp,
// acc 4x4 of 16x16x32. LDS dbuf 152KB -> 1 block/CU, 2 waves/SIMD.
// Per kc-step: ONE barrier. vmcnt(0) at step top drains loads issued a FULL
// STEP earlier (staging is issued after the barrier) -> ~free. Compute is a
// 3-group rotated pipeline: READ_GRP(g+1) is issued BEFORE CLUSTER(g), pinned
// by sched_barrier(0), so ~20 ds_reads are in flight while the matrix pipe
// drains 48 MFMAs (R2/R4 serialized read-bursts against MFMA-bursts; R3's
// unfenced version was erased by the scheduler). WAR register deps order the
// buffer rotation; 2 reg groups live = ~160 VGPR + 64 acc.
// XCD swizzle: bid%8 pins the XCD slot; 4 co-tiles sharing one spatial band
// run on the SAME XCD -> X staging hits that XCD's L2.
__global__ __launch_bounds__(512, 2) void conv_mfma(
    const u16* __restrict__ Xt,    // NHWC bf16 input
    const u16* __restrict__ Wt,    // [9][256][256] bf16
    const float* __restrict__ sv,  // scale[256]
    const float* __restrict__ tv,  // shift[256]
    const float* __restrict__ skip,// NCHW f32 (stage2) or null
    u16* __restrict__ ybf,         // NHWC bf16 out (stage1)
    float* __restrict__ yf,        // NCHW f32 out (stage2)
    const u16* __restrict__ zp, int stage)
{
    __shared__ alignas(16) u16 ldsA[2][9 * 4 * 64 * 8];   // 2 x 36864 B
    __shared__ alignas(16) u16 ldsB[2][40 * 64 * 8];      // 2 x 40960 B

    int t = threadIdx.x;
    int wv = t >> 6, lane = t & 63;
    int q = lane >> 4, n16 = lane & 15;

    // XCD-aware decode: k = bid&7 (XCD slot), co varies within a 32-bid window
    int bid = blockIdx.x;
    int co_t = (bid >> 3) & 3;
    int sp   = ((bid >> 5) << 3) | (bid & 7);   // 0..127 spatial tile
    int h_t  = sp & 1, nb = sp >> 1;
    int co0 = co_t << 6, h0 = h_t << 4;

    // ---- staging assignment (role-split by wave) ----
    const u16* src[10];
    u32 dstOff[10];                 // u16 offset within ldsA/ldsB buffer
    bool isB = (wv < 4);
    int nld = isB ? 10 : 9;
    if (isB) {
#pragma unroll
        for (int j = 0; j < 10; ++j) {
            int g2 = wv * 10 + j;
            int s = g2 * 64 + lane;
            int hi = s / 136, rem = s - hi * 136;
            int wp = rem >> 2, qq = rem & 3;
            int hin = h0 - 1 + hi;
            bool v = (wp >= 1) && (wp <= 32) && (hin >= 0) && (hin < 32);
            src[j] = v ? (Xt + (((nb << 5) + hin) * 32 + (wp - 1)) * 256 + (qq << 3))
                       : (zp + lane * 8);      // zp is 2KB: +kc stays in-bounds
            dstOff[j] = (u32)g2 << 9;
        }
    } else {
#pragma unroll
        for (int i = 0; i < 9; ++i) {
            int g = (wv - 4) * 9 + i;
            int p = g >> 2, mt = g & 3;
            src[i] = Wt + (p << 16) + ((co0 + (mt << 4) + n16) << 8) + (q << 3);
            dstOff[i] = (u32)g << 9;
        }
        src[9] = zp; dstOff[9] = 0;            // unused slot
    }

    f32x4 acc[4][4] = {};

    // prologue: stage kc=0 into buffer 0
    {
        u16* dst = isB ? ldsB[0] : ldsA[0];
#pragma unroll
        for (int j = 0; j < 10; ++j)
            if (j < nld) llds16(&dst[dstOff[j]], src[j]);
    }

    int c = 0;
    for (int kt = 0; kt < 8; ++kt) {
        // buf-c loads were issued one full step ago -> this drain is ~free;
        // barrier makes all waves' loads visible. Nothing fresh is in flight.
        asm volatile("s_waitcnt vmcnt(0)" ::: "memory");
        __builtin_amdgcn_s_barrier();

        const u16* pA = ldsA[c];
        const u16* pB = ldsB[c];

        // issue next-step staging first (writes buf c^1; all waves consumed
        // their c^1 reads before the barrier above)
        if (kt < 7) {
            u16* dstS = isB ? ldsB[c ^ 1] : ldsA[c ^ 1];
            int kc = (kt + 1) << 5;
#pragma unroll
            for (int j = 0; j < 10; ++j)
                if (j < nld) llds16(&dstS[dstOff[j]], src[j] + kc);
        }

        // ---- 3-group rotated burst/cluster pipeline ----
        bf16x8 Bf[2][4][2];
        bf16x8 Af[2][3][4];

        READ_GRP(0, 0);
        __builtin_amdgcn_sched_barrier(0);
        READ_GRP(1, 1);
        __builtin_amdgcn_sched_barrier(0);
        __builtin_amdgcn_s_setprio(1);
        CLUSTER(0);                 // kw=0; covered by RG0, overlaps RG1
        READ_GRP(0, 2);             // reuse buf0 (WAR dep orders after CLUSTER(0))
        __builtin_amdgcn_sched_barrier(0);
        CLUSTER(1);                 // kw=1; overlaps RG(0,2)
        __builtin_amdgcn_sched_barrier(0);
        CLUSTER(0);                 // kw=2 fragments live in buf0
        __builtin_amdgcn_s_setprio(0);
        __builtin_amdgcn_sched_barrier(0);
        c ^= 1;
    }

    // epilogue: C/D layout col=lane&15 (spatial w), row=q*4+reg (c_out)
    if (stage == 1) {
#pragma unroll
        for (int mt = 0; mt < 4; ++mt) {
            int cb = co0 + (mt << 4) + (q << 2);
            f32x4 ss = *(const f32x4*)&sv[cb];
            f32x4 tt = *(const f32x4*)&tv[cb];
#pragma unroll
            for (int nt = 0; nt < 4; ++nt) {
                int h = h0 + (wv << 1) + (nt >> 1), w = ((nt & 1) << 4) + n16;
                ushort4 o;
                o.x = f2bf(fmaxf(acc[mt][nt][0] * ss[0] + tt[0], 0.f));
                o.y = f2bf(fmaxf(acc[mt][nt][1] * ss[1] + tt[1], 0.f));
                o.z = f2bf(fmaxf(acc[mt][nt][2] * ss[2] + tt[2], 0.f));
                o.w = f2bf(fmaxf(acc[mt][nt][3] * ss[3] + tt[3], 0.f));
                *(ushort4*)&ybf[(((nb << 5) + h) * 32 + w) * 256 + cb] = o;
            }
        }
    } else {
#pragma unroll
        for (int mt = 0; mt < 4; ++mt) {
            int cb = co0 + (mt << 4) + (q << 2);
            f32x4 ss = *(const f32x4*)&sv[cb];
            f32x4 tt = *(const f32x4*)&tv[cb];
#pragma unroll
            for (int nt = 0; nt < 4; ++nt) {
                int h = h0 + (wv << 1) + (nt >> 1), w = ((nt & 1) << 4) + n16;
#pragma unroll
                for (int j = 0; j < 4; ++j) {
                    int idx = (((nb << 8) + cb + j) << 10) + (h << 5) + w;
                    yf[idx] = fmaxf(acc[mt][nt][j] * ss[j] + tt[j] + skip[idx], 0.f);
                }
            }
        }
    }
}

extern "C" void kernel_launch(void* const* d_in, const int* in_sizes, int n_in,
                              void* d_out, int out_size, void* d_ws, size_t ws_size,
                              hipStream_t stream) {
    const float* x   = (const float*)d_in[0];
    const float* w1  = (const float*)d_in[1];
    const float* g1  = (const float*)d_in[2];
    const float* b1  = (const float*)d_in[3];
    const float* rm1 = (const float*)d_in[4];
    const float* rv1 = (const float*)d_in[5];
    const float* w2  = (const float*)d_in[6];
    const float* g2  = (const float*)d_in[7];
    const float* b2  = (const float*)d_in[8];
    const float* rm2 = (const float*)d_in[9];
    const float* rv2 = (const float*)d_in[10];

    char* ws = (char*)d_ws;
    u16*  XT  = (u16*)(ws);                    // 32 MB NHWC bf16 x
    u16*  H1  = (u16*)(ws + 33554432);         // 32 MB NHWC bf16 intermediate
    u16*  W1t = (u16*)(ws + 67108864);         // 1.18 MB
    u16*  W2t = (u16*)(ws + 68288512);         // 1.18 MB
    float* sc = (float*)(ws + 69468160);       // s1|t1|s2|t2, 256 f32 each
    u32*  zpg = (u32*)(ws + 69472256);         // 2 KB zeros
    if (ws_size < 69474304) return;            // workspace too small — bail

    prep<<<16896, 256, 0, stream>>>(x, XT, w1, w2, W1t, W2t,
                                    g1, b1, rm1, rv1, g2, b2, rm2, rv2,
                                    sc, zpg);

    conv_mfma<<<512, 512, 0, stream>>>(XT, W1t, sc, sc + 256, nullptr,
                                       H1, nullptr, (const u16*)zpg, 1);
    conv_mfma<<<512, 512, 0, stream>>>(H1, W2t, sc + 512, sc + 768, x,
                                       nullptr, (float*)d_out, (const u16*)zpg, 2);
}

// Round 6
// 267.451 us; speedup vs baseline: 1.1785x; 1.1785x over previous
//
#include <hip/hip_runtime.h>

typedef unsigned short u16;
typedef unsigned int u32;
typedef __attribute__((ext_vector_type(8))) short bf16x8;
typedef __attribute__((ext_vector_type(4))) float f32x4;

__device__ __forceinline__ u16 f2bf(float f) {
    u32 u = __float_as_uint(f);
    u += 0x7fffu + ((u >> 16) & 1u);   // RNE
    return (u16)(u >> 16);
}

__device__ __forceinline__ void llds16(void* l, const void* g) {
    __builtin_amdgcn_global_load_lds(
        (const __attribute__((address_space(1))) u32*)g,
        (__attribute__((address_space(3))) u32*)l, 16, 0, 0);
}

// ---- prep (single dispatch): x NCHW f32 -> NHWC bf16, w -> [p][co][ci] bf16,
//      BN fold (s=g*rsqrt(v+eps), t=b-m*s), 2KB zero page ---------------------
__global__ void prep(const float* __restrict__ x, u16* __restrict__ xt,
                     const float* __restrict__ w1, const float* __restrict__ w2,
                     u16* __restrict__ W1t, u16* __restrict__ W2t,
                     const float* __restrict__ g1, const float* __restrict__ b1,
                     const float* __restrict__ rm1, const float* __restrict__ rv1,
                     const float* __restrict__ g2, const float* __restrict__ b2,
                     const float* __restrict__ rm2, const float* __restrict__ rv2,
                     float* __restrict__ sc, u32* __restrict__ zp) {
    int t = threadIdx.x;
    int b = blockIdx.x;
    if (b < 16384) {
        // x transpose: 64 n * 32 h * 8 cb blocks; 32c x 32w tile via LDS
        __shared__ float xl[32 * 33];
        int n = b >> 8, rem = b & 255;
        int h = rem >> 3, c0 = (rem & 7) << 5;
        int cl = t >> 5, w = t & 31;
#pragma unroll
        for (int i = 0; i < 4; ++i) {
            int c = c0 + i * 8 + cl;
            xl[(i * 8 + cl) * 33 + w] = x[(n * 256 + c) * 1024 + h * 32 + w];
        }
        __syncthreads();
        int wo = t >> 3, k = t & 7;
        ushort4 o;
        o.x = f2bf(xl[(k * 4 + 0) * 33 + wo]);
        o.y = f2bf(xl[(k * 4 + 1) * 33 + wo]);
        o.z = f2bf(xl[(k * 4 + 2) * 33 + wo]);
        o.w = f2bf(xl[(k * 4 + 3) * 33 + wo]);
        *(ushort4*)&xt[((n * 32 + h) * 32 + wo) * 256 + c0 + k * 4] = o;
    } else {
        int bb = b - 16384;                     // 0..511
        int idx = (bb & 255) * 256 + t;         // (co,ci) pair
        const float* src = (bb >> 8) ? w2 : w1;
        u16* dst = (bb >> 8) ? W2t : W1t;
        const float* s = src + idx * 9;
        int co = idx >> 8, ci = idx & 255;
#pragma unroll
        for (int p = 0; p < 9; ++p)
            dst[p * 65536 + co * 256 + ci] = f2bf(s[p]);
        if (bb == 0) {
            float s1 = g1[t] * rsqrtf(rv1[t] + 1e-5f);
            sc[t]       = s1;
            sc[256 + t] = b1[t] - rm1[t] * s1;
            float s2 = g2[t] * rsqrtf(rv2[t] + 1e-5f);
            sc[512 + t] = s2;
            sc[768 + t] = b2[t] - rm2[t] * s2;
            zp[t] = 0u;            // 2KB zero page (512 u32)
            zp[t + 256] = 0u;
        }
    }
}

// ---- main: fused conv3x3 + BN (+skip) + ReLU via MFMA implicit GEMM --------
// Block: 64 c_out x (8h x 32w), 4 waves (256 thr), wave = 64co x 64sp = 4x4
// 16x16x32. Single-buffered LDS 59KB -> 2 blocks/CU = 8 waves/CU = 4 waves/SIMD
// (R1-R5 showed occupancy is the only lever that moved perf; schedules at
// <=2 waves/SIMD all lost).
// New vs R0: staging-under-tail-MFMA. Per step: compute kw=0,1 normally; hoist
// ALL kw=2 LDS reads (20 frags, 80 VGPR) before a MID BARRIER; after it, issue
// next step's 19 llds16 (overwrite safe: all waves' reads done), THEN run the
// 48 tail MFMAs (~2K cyc shadow). Next step's vmcnt(0) drain then waits on
// ~2K-cyc-old loads -> mostly free. Barrier-enforced = compiler-proof (R3),
// register-cheap = no spill (R5). setprio(1) on MFMA clusters: the 2 blocks/CU
// run phase-shifted -> role diversity exists (unlike R4's lockstep).
// XCD swizzle: bid%8 pins the XCD slot; the 4 co-tiles sharing one spatial
// band run on the SAME XCD back-to-back -> X staging hits that XCD's L2.
__global__ __launch_bounds__(256, 2) void conv_mfma(
    const u16* __restrict__ Xt,    // NHWC bf16 input
    const u16* __restrict__ Wt,    // [9][256][256] bf16
    const float* __restrict__ sv,  // scale[256]
    const float* __restrict__ tv,  // shift[256]
    const float* __restrict__ skip,// NCHW f32 (stage2) or null
    u16* __restrict__ ybf,         // NHWC bf16 out (stage1)
    float* __restrict__ yf,        // NCHW f32 out (stage2)
    const u16* __restrict__ zp, int stage)
{
    __shared__ alignas(16) u16 ldsA[9 * 4 * 64 * 8];   // 36 chunks = 36864 B
    __shared__ alignas(16) u16 ldsB[22 * 64 * 8];      // 22 chunks = 22528 B

    int t = threadIdx.x;
    int wv = t >> 6, lane = t & 63;
    int q = lane >> 4, n16 = lane & 15;

    // XCD-aware decode: k = bid&7 (XCD slot), co varies within a 32-bid window
    int bid = blockIdx.x;
    int co_t = (bid >> 3) & 3;
    int sp   = ((bid >> 5) << 3) | (bid & 7);   // 0..255 spatial tile
    int h_t  = sp & 3, nb = sp >> 2;
    int co0 = co_t << 6, h0 = h_t << 3;

    // ---- precompute staging source pointers (kc added in-loop) ----
    // A: 9 chunks/wave; chunk g = wv*9+i -> (p = g>>2, mt = g&3);
    // lane fetches Wt[p][co0 + mt*16 + (lane&15)][ (lane>>4)*8 + kc ]
    const u16* aSrc[9];
#pragma unroll
    for (int i = 0; i < 9; ++i) {
        int g = wv * 9 + i;
        int p = g >> 2, mt = g & 3;
        aSrc[i] = Wt + (p << 16) + ((co0 + (mt << 4) + n16) << 8) + (q << 3);
    }
    // B: 22 chunks total; chunk g2 = wv*6+j (skip g2>=22); slot s = g2*64+lane;
    // s -> hi = s/136, wp = (s%136)>>2, qq = s&3; halo/OOB -> zero page.
    const u16* bSrc[6];
#pragma unroll
    for (int j = 0; j < 6; ++j) {
        int g2 = wv * 6 + j;
        if (g2 < 22) {
            int s = g2 * 64 + lane;
            int hi = s / 136, rem = s - hi * 136;
            int wp = rem >> 2, qq = rem & 3;
            int hin = h0 - 1 + hi;
            bool v = (wp >= 1) && (wp <= 32) && (hin >= 0) && (hin < 32);
            bSrc[j] = v ? (Xt + (((nb << 5) + hin) * 32 + (wp - 1)) * 256 + (qq << 3))
                        : (zp + lane * 8);      // zp is 2KB: +kc stays in-bounds
        } else {
            bSrc[j] = zp + lane * 8;
        }
    }

    f32x4 acc[4][4] = {};

    // prologue: stage kc=0
#pragma unroll
    for (int i = 0; i < 9; ++i)
        llds16(&ldsA[(wv * 9 + i) << 9], aSrc[i]);
#pragma unroll
    for (int j = 0; j < 6; ++j) {
        int g2 = wv * 6 + j;
        if (g2 < 22) llds16(&ldsB[g2 << 9], bSrc[j]);
    }

    for (int kt = 0; kt < 8; ++kt) {
        // staging for this step was issued ~2K cyc ago (under prev tail MFMAs)
        asm volatile("s_waitcnt vmcnt(0)" ::: "memory");
        __builtin_amdgcn_s_barrier();

        // ---- kw = 0,1: R0-style interleaved read/MFMA ----
#pragma unroll
        for (int kw = 0; kw < 2; ++kw) {
            bf16x8 bFr[4][2];
#pragma unroll
            for (int r = 0; r < 4; ++r)
#pragma unroll
                for (int half = 0; half < 2; ++half) {
                    int hi = (wv << 1) + r;
                    int wp = (half << 4) + n16 + kw;
                    bFr[r][half] = *(const bf16x8*)
                        &ldsB[(hi * 136 + (wp << 2) + q) << 3];
                }
            __builtin_amdgcn_s_setprio(1);
#pragma unroll
            for (int kh = 0; kh < 3; ++kh) {
                int p = kh * 3 + kw;
                bf16x8 aF[4];
#pragma unroll
                for (int mt = 0; mt < 4; ++mt)
                    aF[mt] = *(const bf16x8*)&ldsA[((p << 8) + (mt << 6) + lane) << 3];
#pragma unroll
                for (int mt = 0; mt < 4; ++mt)
#pragma unroll
                    for (int nt = 0; nt < 4; ++nt)
                        acc[mt][nt] = __builtin_amdgcn_mfma_f32_16x16x32_bf16(
                            aF[mt], bFr[(nt >> 1) + kh][nt & 1], acc[mt][nt], 0, 0, 0);
            }
            __builtin_amdgcn_s_setprio(0);
        }

        // ---- kw = 2: hoist ALL LDS reads before the mid barrier ----
        bf16x8 bF2[4][2];
        bf16x8 aF2[3][4];
#pragma unroll
        for (int r = 0; r < 4; ++r)
#pragma unroll
            for (int half = 0; half < 2; ++half) {
                int hi = (wv << 1) + r;
                int wp = (half << 4) + n16 + 2;
                bF2[r][half] = *(const bf16x8*)
                    &ldsB[(hi * 136 + (wp << 2) + q) << 3];
            }
#pragma unroll
        for (int kh = 0; kh < 3; ++kh) {
            int p = kh * 3 + 2;
#pragma unroll
            for (int mt = 0; mt < 4; ++mt)
                aF2[kh][mt] = *(const bf16x8*)&ldsA[((p << 8) + (mt << 6) + lane) << 3];
        }
        // my reads must have LANDED before anyone overwrites the buffer
        asm volatile("s_waitcnt lgkmcnt(0)" ::: "memory");
        __builtin_amdgcn_sched_barrier(0);
        __builtin_amdgcn_s_barrier();     // all waves done reading this step

        // issue next step's staging NOW (single buffer, overwrite is safe);
        // the 48 tail MFMAs below shadow its L2 latency + BW
        if (kt < 7) {
            int kc = (kt + 1) << 5;
#pragma unroll
            for (int i = 0; i < 9; ++i)
                llds16(&ldsA[(wv * 9 + i) << 9], aSrc[i] + kc);
#pragma unroll
            for (int j = 0; j < 6; ++j) {
                int g2 = wv * 6 + j;
                if (g2 < 22) llds16(&ldsB[g2 << 9], bSrc[j] + kc);
            }
        }
        __builtin_amdgcn_sched_barrier(0); // keep staging issue before MFMAs

        __builtin_amdgcn_s_setprio(1);
#pragma unroll
        for (int kh = 0; kh < 3; ++kh)
#pragma unroll
            for (int mt = 0; mt < 4; ++mt)
#pragma unroll
                for (int nt = 0; nt < 4; ++nt)
                    acc[mt][nt] = __builtin_amdgcn_mfma_f32_16x16x32_bf16(
                        aF2[kh][mt], bF2[(nt >> 1) + kh][nt & 1], acc[mt][nt], 0, 0, 0);
        __builtin_amdgcn_s_setprio(0);
    }

    // epilogue: C/D layout col=lane&15 (spatial w), row=q*4+reg (c_out)
    if (stage == 1) {
#pragma unroll
        for (int mt = 0; mt < 4; ++mt) {
            int cb = co0 + (mt << 4) + (q << 2);
            f32x4 ss = *(const f32x4*)&sv[cb];
            f32x4 tt = *(const f32x4*)&tv[cb];
#pragma unroll
            for (int nt = 0; nt < 4; ++nt) {
                int h = h0 + (wv << 1) + (nt >> 1), w = ((nt & 1) << 4) + n16;
                ushort4 o;
                o.x = f2bf(fmaxf(acc[mt][nt][0] * ss[0] + tt[0], 0.f));
                o.y = f2bf(fmaxf(acc[mt][nt][1] * ss[1] + tt[1], 0.f));
                o.z = f2bf(fmaxf(acc[mt][nt][2] * ss[2] + tt[2], 0.f));
                o.w = f2bf(fmaxf(acc[mt][nt][3] * ss[3] + tt[3], 0.f));
                *(ushort4*)&ybf[(((nb << 5) + h) * 32 + w) * 256 + cb] = o;
            }
        }
    } else {
#pragma unroll
        for (int mt = 0; mt < 4; ++mt) {
            int cb = co0 + (mt << 4) + (q << 2);
            f32x4 ss = *(const f32x4*)&sv[cb];
            f32x4 tt = *(const f32x4*)&tv[cb];
#pragma unroll
            for (int nt = 0; nt < 4; ++nt) {
                int h = h0 + (wv << 1) + (nt >> 1), w = ((nt & 1) << 4) + n16;
#pragma unroll
                for (int j = 0; j < 4; ++j) {
                    int idx = (((nb << 8) + cb + j) << 10) + (h << 5) + w;
                    yf[idx] = fmaxf(acc[mt][nt][j] * ss[j] + tt[j] + skip[idx], 0.f);
                }
            }
        }
    }
}

extern "C" void kernel_launch(void* const* d_in, const int* in_sizes, int n_in,
                              void* d_out, int out_size, void* d_ws, size_t ws_size,
                              hipStream_t stream) {
    const float* x   = (const float*)d_in[0];
    const float* w1  = (const float*)d_in[1];
    const float* g1  = (const float*)d_in[2];
    const float* b1  = (const float*)d_in[3];
    const float* rm1 = (const float*)d_in[4];
    const float* rv1 = (const float*)d_in[5];
    const float* w2  = (const float*)d_in[6];
    const float* g2  = (const float*)d_in[7];
    const float* b2  = (const float*)d_in[8];
    const float* rm2 = (const float*)d_in[9];
    const float* rv2 = (const float*)d_in[10];

    char* ws = (char*)d_ws;
    u16*  XT  = (u16*)(ws);                    // 32 MB NHWC bf16 x
    u16*  H1  = (u16*)(ws + 33554432);         // 32 MB NHWC bf16 intermediate
    u16*  W1t = (u16*)(ws + 67108864);         // 1.18 MB
    u16*  W2t = (u16*)(ws + 68288512);         // 1.18 MB
    float* sc = (float*)(ws + 69468160);       // s1|t1|s2|t2, 256 f32 each
    u32*  zpg = (u32*)(ws + 69472256);         // 2 KB zeros
    if (ws_size < 69474304) return;            // workspace too small — bail

    prep<<<16896, 256, 0, stream>>>(x, XT, w1, w2, W1t, W2t,
                                    g1, b1, rm1, rv1, g2, b2, rm2, rv2,
                                    sc, zpg);

    conv_mfma<<<1024, 256, 0, stream>>>(XT, W1t, sc, sc + 256, nullptr,
                                        H1, nullptr, (const u16*)zpg, 1);
    conv_mfma<<<1024, 256, 0, stream>>>(H1, W2t, sc + 512, sc + 768, x,
                                        nullptr, (float*)d_out, (const u16*)zpg, 2);
}